// Round 7
// baseline (262.149 us; speedup 1.0000x reference)
//
#include <hip/hip_runtime.h>
#include <hip/hip_bf16.h>

#define BB 8
#define QQ 64
#define SS 64
#define TT 64
#define HH 8
#define DH 64
#define NHID 512
#define STAT_K 8
#define TOKEN_K 16

typedef short bf16x8 __attribute__((ext_vector_type(8)));
typedef float f32x4 __attribute__((ext_vector_type(4)));

__device__ inline ushort f2bf_rne(float x) {
    union { float f; unsigned u; } v; v.f = x;
    unsigned r = v.u + 0x7fff + ((v.u >> 16) & 1);
    return (ushort)(r >> 16);
}
__device__ inline float bf2f(ushort h) {
    union { unsigned u; float f; } v; v.u = ((unsigned)h) << 16;
    return v.f;
}

// ---------------------------------------------------------------------------
// Transpose+split the six 512x512 weights into bf16 hi/lo planes:
// per z: hi[n][k] (262144 ush) then lo[n][k].
// ---------------------------------------------------------------------------
__global__ __launch_bounds__(256) void conv_w(
    const float* w0, const float* w1, const float* w2,
    const float* w3, const float* w4, const float* w5, ushort* wT)
{
    const int z = blockIdx.z;
    const float* srcs[6] = {w0, w1, w2, w3, w4, w5};
    const float* src = srcs[z];
    ushort* hi = wT + (size_t)z * 524288;
    ushort* lo = hi + 262144;
    __shared__ float t[32][33];
    const int c0 = blockIdx.x * 32, r0 = blockIdx.y * 32;
    const int tx = threadIdx.x & 31, ty = threadIdx.x >> 5;
    #pragma unroll
    for (int i = 0; i < 4; ++i)
        t[ty + 8 * i][tx] = src[(r0 + ty + 8 * i) * 512 + c0 + tx];
    __syncthreads();
    #pragma unroll
    for (int i = 0; i < 4; ++i) {
        float x = t[tx][ty + 8 * i];
        ushort h = f2bf_rne(x);
        int o = (c0 + ty + 8 * i) * 512 + r0 + tx;
        hi[o] = h;
        lo[o] = f2bf_rne(x - bf2f(h));
    }
}

// ---------------------------------------------------------------------------
// z-batched split-bf16 MFMA GEMM (fp32-equivalent): 512x512x512. fp32 A is
// converted to hi/lo inline in the staging path. Load-after-barrier (R5
// showed hand-prefetch regresses 2x here).
// z=0: q @ Wq_stat ; z=1: sk @ Wk_stat ; z=2: q @ Wq_token.
// ---------------------------------------------------------------------------
__global__ __launch_bounds__(256) void gemm_split3(
    const float* __restrict__ queries, const float* __restrict__ stat_keys,
    const ushort* __restrict__ wT,
    float* __restrict__ q_stat, float* __restrict__ k_stat,
    float* __restrict__ q_tokf)
{
    const int z = blockIdx.z;
    const float* Afp = (z == 1) ? stat_keys : queries;
    const ushort* Bh = wT + (size_t)z * 524288;
    const ushort* Bl = Bh + 262144;
    float* C = (z == 0) ? q_stat : (z == 1) ? k_stat : q_tokf;
    const int K = 512, N = 512;

    __shared__ ushort As[2][64][40];
    __shared__ ushort Bs[2][64][40];
    const int tid = threadIdx.x;
    const int row0 = blockIdx.y * 64, col0 = blockIdx.x * 64;
    const int wave = tid >> 6, lane = tid & 63;
    const int wm = wave & 1, wn = wave >> 1;
    const int m16 = lane & 15, quad = lane >> 4;
    const int srow = tid >> 2, schunk = tid & 3;

    const float*  aptr  = Afp + (size_t)(row0 + srow) * K + schunk * 8;
    const ushort* bptrh = Bh + (size_t)(col0 + srow) * K + schunk * 8;
    const ushort* bptrl = Bl + (size_t)(col0 + srow) * K + schunk * 8;

    f32x4 acc[2][2];
    #pragma unroll
    for (int i = 0; i < 2; ++i)
        #pragma unroll
        for (int j = 0; j < 2; ++j)
            #pragma unroll
            for (int r = 0; r < 4; ++r) acc[i][j][r] = 0.f;

    for (int k0 = 0; k0 < K; k0 += 32) {
        float4 ax0 = ((const float4*)(aptr + k0))[0];
        float4 ax1 = ((const float4*)(aptr + k0))[1];
        uint4  bvh = *(const uint4*)(bptrh + k0);
        uint4  bvl = *(const uint4*)(bptrl + k0);
        ushort4 h0, h1, l0, l1;
        h0.x = f2bf_rne(ax0.x); l0.x = f2bf_rne(ax0.x - bf2f(h0.x));
        h0.y = f2bf_rne(ax0.y); l0.y = f2bf_rne(ax0.y - bf2f(h0.y));
        h0.z = f2bf_rne(ax0.z); l0.z = f2bf_rne(ax0.z - bf2f(h0.z));
        h0.w = f2bf_rne(ax0.w); l0.w = f2bf_rne(ax0.w - bf2f(h0.w));
        h1.x = f2bf_rne(ax1.x); l1.x = f2bf_rne(ax1.x - bf2f(h1.x));
        h1.y = f2bf_rne(ax1.y); l1.y = f2bf_rne(ax1.y - bf2f(h1.y));
        h1.z = f2bf_rne(ax1.z); l1.z = f2bf_rne(ax1.z - bf2f(h1.z));
        h1.w = f2bf_rne(ax1.w); l1.w = f2bf_rne(ax1.w - bf2f(h1.w));
        *(ushort4*)&As[0][srow][schunk * 8]     = h0;
        *(ushort4*)&As[0][srow][schunk * 8 + 4] = h1;
        *(ushort4*)&As[1][srow][schunk * 8]     = l0;
        *(ushort4*)&As[1][srow][schunk * 8 + 4] = l1;
        *(uint4*)&Bs[0][srow][schunk * 8] = bvh;
        *(uint4*)&Bs[1][srow][schunk * 8] = bvl;
        __syncthreads();

        bf16x8 af[2], bf[2], afl[2], bfl[2];
        #pragma unroll
        for (int i = 0; i < 2; ++i) {
            af[i]  = *(const bf16x8*)&As[0][wm * 32 + i * 16 + m16][quad * 8];
            bf[i]  = *(const bf16x8*)&Bs[0][wn * 32 + i * 16 + m16][quad * 8];
            afl[i] = *(const bf16x8*)&As[1][wm * 32 + i * 16 + m16][quad * 8];
            bfl[i] = *(const bf16x8*)&Bs[1][wn * 32 + i * 16 + m16][quad * 8];
        }
        #pragma unroll
        for (int i = 0; i < 2; ++i)
            #pragma unroll
            for (int j = 0; j < 2; ++j) {
                acc[i][j] = __builtin_amdgcn_mfma_f32_16x16x32_bf16(af[i], bf[j], acc[i][j], 0, 0, 0);
                acc[i][j] = __builtin_amdgcn_mfma_f32_16x16x32_bf16(af[i], bfl[j], acc[i][j], 0, 0, 0);
                acc[i][j] = __builtin_amdgcn_mfma_f32_16x16x32_bf16(afl[i], bf[j], acc[i][j], 0, 0, 0);
            }
        __syncthreads();
    }

    #pragma unroll
    for (int i = 0; i < 2; ++i)
        #pragma unroll
        for (int j = 0; j < 2; ++j) {
            int r0 = row0 + wm * 32 + i * 16 + quad * 4;
            int c = col0 + wn * 32 + j * 16 + m16;
            #pragma unroll
            for (int reg = 0; reg < 4; ++reg)
                C[(size_t)(r0 + reg) * N + c] = acc[i][j][reg];
        }
}

// ---------------------------------------------------------------------------
// Final split GEMM: out = ctx(hi/lo) @ Wo(hi/lo), 512x512x512 -> fp32.
// ---------------------------------------------------------------------------
__global__ __launch_bounds__(256) void gemm_out(
    const ushort* __restrict__ Ah, const ushort* __restrict__ Al,
    const ushort* __restrict__ Bh, const ushort* __restrict__ Bl,
    float* __restrict__ C)
{
    const int K = 512, N = 512;
    __shared__ ushort As[2][64][40];
    __shared__ ushort Bs[2][64][40];
    const int tid = threadIdx.x;
    const int row0 = blockIdx.y * 64, col0 = blockIdx.x * 64;
    const int wave = tid >> 6, lane = tid & 63;
    const int wm = wave & 1, wn = wave >> 1;
    const int m16 = lane & 15, quad = lane >> 4;
    const int srow = tid >> 2, schunk = tid & 3;

    f32x4 acc[2][2];
    #pragma unroll
    for (int i = 0; i < 2; ++i)
        #pragma unroll
        for (int j = 0; j < 2; ++j)
            #pragma unroll
            for (int r = 0; r < 4; ++r) acc[i][j][r] = 0.f;

    for (int k0 = 0; k0 < K; k0 += 32) {
        const size_t aoff = (size_t)(row0 + srow) * K + k0 + schunk * 8;
        const size_t boff = (size_t)(col0 + srow) * K + k0 + schunk * 8;
        *(uint4*)&As[0][srow][schunk * 8] = *(const uint4*)(Ah + aoff);
        *(uint4*)&Bs[0][srow][schunk * 8] = *(const uint4*)(Bh + boff);
        *(uint4*)&As[1][srow][schunk * 8] = *(const uint4*)(Al + aoff);
        *(uint4*)&Bs[1][srow][schunk * 8] = *(const uint4*)(Bl + boff);
        __syncthreads();

        bf16x8 af[2], bf[2], afl[2], bfl[2];
        #pragma unroll
        for (int i = 0; i < 2; ++i) {
            af[i]  = *(const bf16x8*)&As[0][wm * 32 + i * 16 + m16][quad * 8];
            bf[i]  = *(const bf16x8*)&Bs[0][wn * 32 + i * 16 + m16][quad * 8];
            afl[i] = *(const bf16x8*)&As[1][wm * 32 + i * 16 + m16][quad * 8];
            bfl[i] = *(const bf16x8*)&Bs[1][wn * 32 + i * 16 + m16][quad * 8];
        }
        #pragma unroll
        for (int i = 0; i < 2; ++i)
            #pragma unroll
            for (int j = 0; j < 2; ++j) {
                acc[i][j] = __builtin_amdgcn_mfma_f32_16x16x32_bf16(af[i], bf[j], acc[i][j], 0, 0, 0);
                acc[i][j] = __builtin_amdgcn_mfma_f32_16x16x32_bf16(af[i], bfl[j], acc[i][j], 0, 0, 0);
                acc[i][j] = __builtin_amdgcn_mfma_f32_16x16x32_bf16(afl[i], bf[j], acc[i][j], 0, 0, 0);
            }
        __syncthreads();
    }

    #pragma unroll
    for (int i = 0; i < 2; ++i)
        #pragma unroll
        for (int j = 0; j < 2; ++j) {
            int r0 = row0 + wm * 32 + i * 16 + quad * 4;
            int c = col0 + wn * 32 + j * 16 + m16;
            #pragma unroll
            for (int reg = 0; reg < 4; ++reg)
                C[(size_t)(r0 + reg) * N + c] = acc[i][j][reg];
        }
}

// ---------------------------------------------------------------------------
// K-token projection (R4 structure): k_tok[(s,t),(h,d)] = tok_keys @ Wk_token
// 64x256 tile, fused fp32->bf16 A staging. Row map: r -> (r>>4)*64+48+(r&15).
// ---------------------------------------------------------------------------
__global__ __launch_bounds__(256) void gemm_tok(
    const float* __restrict__ token_keys, const ushort* __restrict__ wkt_h,
    ushort* __restrict__ k_tok)
{
    const int K = 512, N = 512;
    __shared__ ushort As[64][40];
    __shared__ ushort Bs[256][40];
    const int tid = threadIdx.x;
    const int row0 = blockIdx.y * 64, col0 = blockIdx.x * 256;
    const int wave = tid >> 6, lane = tid & 63;
    const int m16 = lane & 15, quad = lane >> 4;
    const int srow = tid >> 2, schunk = tid & 3;

    const int r = row0 + srow;
    const size_t arow = (size_t)((r >> 4) * 64 + 48 + (r & 15)) * K;

    f32x4 acc[4][4];
    #pragma unroll
    for (int i = 0; i < 4; ++i)
        #pragma unroll
        for (int j = 0; j < 4; ++j)
            #pragma unroll
            for (int rr = 0; rr < 4; ++rr) acc[i][j][rr] = 0.f;

    for (int k0 = 0; k0 < K; k0 += 32) {
        const float* ap = token_keys + arow + k0 + schunk * 8;
        float4 x0 = ((const float4*)ap)[0];
        float4 x1 = ((const float4*)ap)[1];
        ushort4 h0, h1;
        h0.x = f2bf_rne(x0.x); h0.y = f2bf_rne(x0.y);
        h0.z = f2bf_rne(x0.z); h0.w = f2bf_rne(x0.w);
        h1.x = f2bf_rne(x1.x); h1.y = f2bf_rne(x1.y);
        h1.z = f2bf_rne(x1.z); h1.w = f2bf_rne(x1.w);
        *(ushort4*)&As[srow][schunk * 8] = h0;
        *(ushort4*)&As[srow][schunk * 8 + 4] = h1;
        #pragma unroll
        for (int i = 0; i < 4; ++i) {
            int v = tid + i * 256;
            int brow = v >> 2, bchunk = v & 3;
            *(uint4*)&Bs[brow][bchunk * 8] =
                *(const uint4*)(wkt_h + (size_t)(col0 + brow) * K + k0 + bchunk * 8);
        }
        __syncthreads();

        bf16x8 af[4], bf[4];
        #pragma unroll
        for (int i = 0; i < 4; ++i) {
            af[i] = *(const bf16x8*)&As[i * 16 + m16][quad * 8];
            bf[i] = *(const bf16x8*)&Bs[wave * 64 + i * 16 + m16][quad * 8];
        }
        #pragma unroll
        for (int i = 0; i < 4; ++i)
            #pragma unroll
            for (int j = 0; j < 4; ++j)
                acc[i][j] = __builtin_amdgcn_mfma_f32_16x16x32_bf16(af[i], bf[j], acc[i][j], 0, 0, 0);
        __syncthreads();
    }

    #pragma unroll
    for (int i = 0; i < 4; ++i)
        #pragma unroll
        for (int j = 0; j < 4; ++j) {
            int r0 = row0 + i * 16 + quad * 4;
            int c = col0 + wave * 64 + j * 16 + m16;
            #pragma unroll
            for (int reg = 0; reg < 4; ++reg)
                k_tok[(size_t)(r0 + reg) * N + c] = f2bf_rne(acc[i][j][reg]);
        }
}

// ---------------------------------------------------------------------------
// V projection TRANSPOSED: Vt[(h,d), (s,t)] = Wv^T @ values^T.
// A = wv_h plane rows ((h,d) x e, bf16, contiguous). B^T = raw values rows
// ((s,t) x e, fp32->bf16 inline, last-16 row map). Tile 256(M) x 64(N):
// values re-read only x2; wv L2-resident. Output rows (h,d), stride 8192.
// ---------------------------------------------------------------------------
__global__ __launch_bounds__(256) void gemm_vT(
    const float* __restrict__ values, const ushort* __restrict__ wv_h,
    ushort* __restrict__ vT)
{
    const int K = 512;
    __shared__ ushort As[256][40];
    __shared__ ushort Bs[64][40];
    const int tid = threadIdx.x;
    const int row0m = blockIdx.y * 256, col0n = blockIdx.x * 64;
    const int wave = tid >> 6, lane = tid & 63;
    const int m16 = lane & 15, quad = lane >> 4;
    const int srow = tid >> 2, schunk = tid & 3;

    const int n = col0n + srow;
    const size_t brow = (size_t)((n >> 4) * 64 + 48 + (n & 15)) * K;

    f32x4 acc[4][4];
    #pragma unroll
    for (int i = 0; i < 4; ++i)
        #pragma unroll
        for (int j = 0; j < 4; ++j)
            #pragma unroll
            for (int rr = 0; rr < 4; ++rr) acc[i][j][rr] = 0.f;

    for (int k0 = 0; k0 < K; k0 += 32) {
        // B: 64 (s,t) rows x 32 e, fp32 -> bf16
        const float* bp = values + brow + k0 + schunk * 8;
        float4 x0 = ((const float4*)bp)[0];
        float4 x1 = ((const float4*)bp)[1];
        ushort4 h0, h1;
        h0.x = f2bf_rne(x0.x); h0.y = f2bf_rne(x0.y);
        h0.z = f2bf_rne(x0.z); h0.w = f2bf_rne(x0.w);
        h1.x = f2bf_rne(x1.x); h1.y = f2bf_rne(x1.y);
        h1.z = f2bf_rne(x1.z); h1.w = f2bf_rne(x1.w);
        *(ushort4*)&Bs[srow][schunk * 8] = h0;
        *(ushort4*)&Bs[srow][schunk * 8 + 4] = h1;
        // A: 256 (h,d) rows x 32 e from wv plane
        #pragma unroll
        for (int i = 0; i < 4; ++i) {
            int v = tid + i * 256;
            int ar = v >> 2, ac = v & 3;
            *(uint4*)&As[ar][ac * 8] =
                *(const uint4*)(wv_h + (size_t)(row0m + ar) * K + k0 + ac * 8);
        }
        __syncthreads();

        bf16x8 af[4], bf[4];
        #pragma unroll
        for (int i = 0; i < 4; ++i) {
            af[i] = *(const bf16x8*)&As[wave * 64 + i * 16 + m16][quad * 8];
            bf[i] = *(const bf16x8*)&Bs[i * 16 + m16][quad * 8];
        }
        #pragma unroll
        for (int i = 0; i < 4; ++i)
            #pragma unroll
            for (int j = 0; j < 4; ++j)
                acc[i][j] = __builtin_amdgcn_mfma_f32_16x16x32_bf16(af[i], bf[j], acc[i][j], 0, 0, 0);
        __syncthreads();
    }

    #pragma unroll
    for (int i = 0; i < 4; ++i)
        #pragma unroll
        for (int j = 0; j < 4; ++j) {
            int m = row0m + wave * 64 + i * 16 + quad * 4;
            int c = col0n + j * 16 + m16;
            #pragma unroll
            for (int reg = 0; reg < 4; ++reg)
                vT[(size_t)(m + reg) * 8192 + c] = f2bf_rne(acc[i][j][reg]);
        }
}

// ---------------------------------------------------------------------------
// Dense MFMA attention: one 256-thread wg per (b,h,qtile of 16 q). Stat
// top-8 (bit-identical fp32 VALU path) -> wseg[16][64] (0 if unselected).
// Token scores for ALL 64 segs via MFMA (q hi/lo-split = fp32 q precision),
// softmax in C-frag layout via 16-lane shuffles, comb (hi/lo bf16) -> LDS,
// PV GEMM vs Vt. Two k-halves to fit LDS <= 64 KB.
// ---------------------------------------------------------------------------
__global__ __launch_bounds__(256) void attend_mfma(
    const float* __restrict__ q_stat, const float* __restrict__ k_stat,
    const float* __restrict__ q_tokf, const ushort* __restrict__ k_tok,
    const ushort* __restrict__ vT, const int* __restrict__ valid_lens,
    ushort* __restrict__ ctx_hi, ushort* __restrict__ ctx_lo)
{
    const int wg = blockIdx.x;
    const int b = wg >> 5, h = (wg >> 2) & 7, qt = wg & 3;
    const int tid = threadIdx.x, wave = tid >> 6, lane = tid & 63;
    const int m16 = lane & 15, quad = lane >> 4;

    __shared__ float  sQs[16][64];       // q_stat tile (broadcast reads)
    __shared__ ushort sQt[2][16][72];    // q_tok hi/lo bf16
    __shared__ float  sW[16][64];        // per-q segment weights (0 if not top-8)
    __shared__ ushort sKt[128][72];      // k_tok stage: 8 segs x 16 tok x 64 d
    __shared__ ushort sCb[2][16][520];   // comb hi/lo, one k-half (512)

    // ---- P0: stage q_stat + q_tok(hi/lo) tiles ----
    {
        int row = tid >> 4, c4 = tid & 15;
        const size_t qrow = (size_t)(b * 64 + qt * 16 + row) * 512 + h * 64;
        float4 xs = *(const float4*)(q_stat + qrow + c4 * 4);
        *(float4*)&sQs[row][c4 * 4] = xs;
        float4 xt = *(const float4*)(q_tokf + qrow + c4 * 4);
        ushort4 hh, ll;
        hh.x = f2bf_rne(xt.x); ll.x = f2bf_rne(xt.x - bf2f(hh.x));
        hh.y = f2bf_rne(xt.y); ll.y = f2bf_rne(xt.y - bf2f(hh.y));
        hh.z = f2bf_rne(xt.z); ll.z = f2bf_rne(xt.z - bf2f(hh.z));
        hh.w = f2bf_rne(xt.w); ll.w = f2bf_rne(xt.w - bf2f(hh.w));
        *(ushort4*)&sQt[0][row][c4 * 4] = hh;
        *(ushort4*)&sQt[1][row][c4 * 4] = ll;
    }
    __syncthreads();

    // ---- A-frags for score GEMM (lane m = q = m16) ----
    bf16x8 aQh[2], aQl[2];
    #pragma unroll
    for (int ks = 0; ks < 2; ++ks) {
        aQh[ks] = *(const bf16x8*)&sQt[0][m16][ks * 32 + quad * 8];
        aQl[ks] = *(const bf16x8*)&sQt[1][m16][ks * 32 + quad * 8];
    }

    // ---- P1/P2: stat scores + top-8 (lane = segment s; 4 q per wave) ----
    const int vlen = valid_lens[b];
    for (int qq = 0; qq < 4; ++qq) {
        const int q = wave * 4 + qq;
        const float4* kr = (const float4*)(k_stat + (size_t)(b * SS + lane) * NHID + h * DH);
        const float4* sq4 = (const float4*)&sQs[q][0];
        float sc = 0.f;
        #pragma unroll
        for (int i = 0; i < 16; ++i) {
            float4 a = sq4[i], kk = kr[i];
            sc += a.x * kk.x + a.y * kk.y + a.z * kk.z + a.w * kk.w;
        }
        sc *= 0.125f;
        if (lane >= vlen) sc = -1e6f;

        float my = sc;
        float mv[STAT_K]; int mi[STAT_K];
        #pragma unroll
        for (int j = 0; j < STAT_K; ++j) {
            float v = my; int idx = lane;
            #pragma unroll
            for (int off = 32; off > 0; off >>= 1) {
                float ov = __shfl_down(v, off);
                int   oi = __shfl_down(idx, off);
                if (ov > v || (ov == v && oi < idx)) { v = ov; idx = oi; }
            }
            v = __shfl(v, 0); idx = __shfl(idx, 0);
            mv[j] = v; mi[j] = idx;
            if (lane == idx) my = -3e38f;
        }
        float m0 = mv[0], den = 0.f, w[STAT_K];
        #pragma unroll
        for (int j = 0; j < STAT_K; ++j) { w[j] = __expf(mv[j] - m0); den += w[j]; }
        float inv = 1.f / den;
        float wl = 0.f;
        #pragma unroll
        for (int j = 0; j < STAT_K; ++j)
            if (lane == mi[j]) wl = w[j] * inv;
        sW[q][lane] = wl;
    }

    // ---- P3/P4: token scores + softmax + comb, then PV (two k-halves) ----
    f32x4 oacc;
    #pragma unroll
    for (int r = 0; r < 4; ++r) oacc[r] = 0.f;

    const ushort* vrow = vT + (size_t)(h * 64 + wave * 16 + m16) * 8192
                            + (size_t)b * 1024 + quad * 8;

    for (int half = 0; half < 2; ++half) {
        for (int g = 0; g < 4; ++g) {
            __syncthreads();   // protects sKt reuse, sW (first), sCb (across halves)
            // stage 8 segs x 16 tok x 64 d of k_tok
            {
                const ushort* base = k_tok
                    + (size_t)(b * 1024 + half * 512 + g * 128) * 512 + h * 64;
                #pragma unroll
                for (int i = 0; i < 4; ++i) {
                    int idx = i * 256 + tid;
                    int row = idx >> 3, ch = idx & 7;
                    *(uint4*)&sKt[row][ch * 8] =
                        *(const uint4*)(base + (size_t)row * 512 + ch * 8);
                }
            }
            __syncthreads();

            #pragma unroll
            for (int ti = 0; ti < 2; ++ti) {
                const int sl = wave * 2 + ti;              // seg within group
                const int sg = half * 32 + g * 8 + sl;     // global seg
                bf16x8 b0 = *(const bf16x8*)&sKt[sl * 16 + m16][quad * 8];
                bf16x8 b1 = *(const bf16x8*)&sKt[sl * 16 + m16][32 + quad * 8];
                f32x4 c;
                #pragma unroll
                for (int r = 0; r < 4; ++r) c[r] = 0.f;
                c = __builtin_amdgcn_mfma_f32_16x16x32_bf16(aQh[0], b0, c, 0, 0, 0);
                c = __builtin_amdgcn_mfma_f32_16x16x32_bf16(aQl[0], b0, c, 0, 0, 0);
                c = __builtin_amdgcn_mfma_f32_16x16x32_bf16(aQh[1], b1, c, 0, 0, 0);
                c = __builtin_amdgcn_mfma_f32_16x16x32_bf16(aQl[1], b1, c, 0, 0, 0);

                const int klb = (g * 8 + sl) * 16 + m16;   // k index within half
                #pragma unroll
                for (int r = 0; r < 4; ++r) {
                    float v = c[r] * 0.125f;
                    float m = v;
                    m = fmaxf(m, __shfl_xor(m, 1));
                    m = fmaxf(m, __shfl_xor(m, 2));
                    m = fmaxf(m, __shfl_xor(m, 4));
                    m = fmaxf(m, __shfl_xor(m, 8));
                    float e = __expf(v - m);
                    float s = e;
                    s += __shfl_xor(s, 1);
                    s += __shfl_xor(s, 2);
                    s += __shfl_xor(s, 4);
                    s += __shfl_xor(s, 8);
                    float wt = (e / s) * sW[quad * 4 + r][sg];
                    ushort ch = f2bf_rne(wt);
                    sCb[0][quad * 4 + r][klb] = ch;
                    sCb[1][quad * 4 + r][klb] = f2bf_rne(wt - bf2f(ch));
                }
            }
        }
        __syncthreads();   // sCb complete for this half

        // PV partial: out[q][d(wave*16+m16)] += comb(hi/lo) x Vt
        #pragma unroll
        for (int ks = 0; ks < 16; ++ks) {
            bf16x8 bv = *(const bf16x8*)(vrow + half * 512 + ks * 32);
            bf16x8 ah = *(const bf16x8*)&sCb[0][m16][ks * 32 + quad * 8];
            bf16x8 al = *(const bf16x8*)&sCb[1][m16][ks * 32 + quad * 8];
            oacc = __builtin_amdgcn_mfma_f32_16x16x32_bf16(ah, bv, oacc, 0, 0, 0);
            oacc = __builtin_amdgcn_mfma_f32_16x16x32_bf16(al, bv, oacc, 0, 0, 0);
        }
    }

    // ---- epilogue: ctx hi/lo ----
    #pragma unroll
    for (int r = 0; r < 4; ++r) {
        const size_t o = (size_t)(b * 64 + qt * 16 + quad * 4 + r) * 512
                       + h * 64 + wave * 16 + m16;
        ushort hh = f2bf_rne(oacc[r]);
        ctx_hi[o] = hh;
        ctx_lo[o] = f2bf_rne(oacc[r] - bf2f(hh));
    }
}

extern "C" void kernel_launch(void* const* d_in, const int* in_sizes, int n_in,
                              void* d_out, int out_size, void* d_ws, size_t ws_size,
                              hipStream_t stream) {
    const float* queries    = (const float*)d_in[0];
    const float* stat_keys  = (const float*)d_in[1];
    const float* token_keys = (const float*)d_in[2];
    const float* values     = (const float*)d_in[3];
    const int*   valid_lens = (const int*)d_in[4];
    const float* Wq_stat    = (const float*)d_in[5];
    const float* Wq_token   = (const float*)d_in[6];
    const float* Wk_stat    = (const float*)d_in[7];
    const float* Wk_token   = (const float*)d_in[8];
    const float* Wv         = (const float*)d_in[9];
    const float* Wo         = (const float*)d_in[10];

    char* w = (char*)d_ws;
    ushort* wT      = (ushort*)(w + 0);            // 6 x (hi+lo) x 262144 ush = 6 MB
    float*  q_stat  = (float*)(w + 6291456);
    float*  k_stat  = (float*)(w + 7340032);
    float*  q_tokf  = (float*)(w + 8388608);
    ushort* k_tok   = (ushort*)(w + 9437184);      // bf16 [8192,512]
    ushort* vT      = (ushort*)(w + 17825792);     // bf16 [512,8192] (transposed)
    ushort* ctx_hi  = (ushort*)(w + 26214400);
    ushort* ctx_lo  = ctx_hi + 262144;

    // weight order in wT: 0=Wq_stat 1=Wk_stat 2=Wq_token 3=Wk_token 4=Wv 5=Wo
    ushort* wkt_h = wT + 3 * 524288;
    ushort* wv_h  = wT + 4 * 524288;
    ushort* wo_h  = wT + 5 * 524288, *wo_l = wo_h + 262144;

    // 1. weight transpose+split
    conv_w<<<dim3(16, 16, 6), 256, 0, stream>>>(
        Wq_stat, Wk_stat, Wq_token, Wk_token, Wv, Wo, wT);

    // 2. q_stat / k_stat / q_tok projections (fp32-equivalent)
    gemm_split3<<<dim3(8, 8, 3), 256, 0, stream>>>(
        queries, stat_keys, wT, q_stat, k_stat, q_tokf);

    // 3a. K-token projection (row layout, for score-GEMM B-frags)
    gemm_tok<<<dim3(2, 128), 256, 0, stream>>>(token_keys, wkt_h, k_tok);

    // 3b. V projection, transposed output (for PV B-frags)
    gemm_vT<<<dim3(128, 2), 256, 0, stream>>>(values, wv_h, vT);

    // 4. dense MFMA attention (stat top-8 + token softmax + PV)
    attend_mfma<<<256, 256, 0, stream>>>(
        q_stat, k_stat, q_tokf, k_tok, vT, valid_lens, ctx_hi, ctx_lo);

    // 5. output projection
    gemm_out<<<dim3(8, 8), 256, 0, stream>>>(
        ctx_hi, ctx_lo, wo_h, wo_l, (float*)d_out);
}

// Round 8
// 261.719 us; speedup vs baseline: 1.0016x; 1.0016x over previous
//
#include <hip/hip_runtime.h>
#include <hip/hip_bf16.h>

#define BB 8
#define QQ 64
#define SS 64
#define TT 64
#define HH 8
#define DH 64
#define NHID 512
#define STAT_K 8
#define TOKEN_K 16

typedef short bf16x8 __attribute__((ext_vector_type(8)));
typedef float f32x4 __attribute__((ext_vector_type(4)));

__device__ inline ushort f2bf_rne(float x) {
    union { float f; unsigned u; } v; v.f = x;
    unsigned r = v.u + 0x7fff + ((v.u >> 16) & 1);
    return (ushort)(r >> 16);
}
__device__ inline float bf2f(ushort h) {
    union { unsigned u; float f; } v; v.u = ((unsigned)h) << 16;
    return v.f;
}

// ---------------------------------------------------------------------------
// Transpose+split the six 512x512 weights into bf16 hi/lo planes.
// ---------------------------------------------------------------------------
__global__ __launch_bounds__(256) void conv_w(
    const float* w0, const float* w1, const float* w2,
    const float* w3, const float* w4, const float* w5, ushort* wT)
{
    const int z = blockIdx.z;
    const float* srcs[6] = {w0, w1, w2, w3, w4, w5};
    const float* src = srcs[z];
    ushort* hi = wT + (size_t)z * 524288;
    ushort* lo = hi + 262144;
    __shared__ float t[32][33];
    const int c0 = blockIdx.x * 32, r0 = blockIdx.y * 32;
    const int tx = threadIdx.x & 31, ty = threadIdx.x >> 5;
    #pragma unroll
    for (int i = 0; i < 4; ++i)
        t[ty + 8 * i][tx] = src[(r0 + ty + 8 * i) * 512 + c0 + tx];
    __syncthreads();
    #pragma unroll
    for (int i = 0; i < 4; ++i) {
        float x = t[tx][ty + 8 * i];
        ushort h = f2bf_rne(x);
        int o = (c0 + ty + 8 * i) * 512 + r0 + tx;
        hi[o] = h;
        lo[o] = f2bf_rne(x - bf2f(h));
    }
}

// ---------------------------------------------------------------------------
// z-batched split-bf16 MFMA GEMM (fp32-equivalent): 512x512x512. fp32 A
// converted hi/lo inline. Load-after-barrier (R5: no hand-prefetch).
// ---------------------------------------------------------------------------
__global__ __launch_bounds__(256) void gemm_split3(
    const float* __restrict__ queries, const float* __restrict__ stat_keys,
    const ushort* __restrict__ wT,
    float* __restrict__ q_stat, float* __restrict__ k_stat,
    float* __restrict__ q_tokf)
{
    const int z = blockIdx.z;
    const float* Afp = (z == 1) ? stat_keys : queries;
    const ushort* Bh = wT + (size_t)z * 524288;
    const ushort* Bl = Bh + 262144;
    float* C = (z == 0) ? q_stat : (z == 1) ? k_stat : q_tokf;
    const int K = 512, N = 512;

    __shared__ ushort As[2][64][40];
    __shared__ ushort Bs[2][64][40];
    const int tid = threadIdx.x;
    const int row0 = blockIdx.y * 64, col0 = blockIdx.x * 64;
    const int wave = tid >> 6, lane = tid & 63;
    const int wm = wave & 1, wn = wave >> 1;
    const int m16 = lane & 15, quad = lane >> 4;
    const int srow = tid >> 2, schunk = tid & 3;

    const float*  aptr  = Afp + (size_t)(row0 + srow) * K + schunk * 8;
    const ushort* bptrh = Bh + (size_t)(col0 + srow) * K + schunk * 8;
    const ushort* bptrl = Bl + (size_t)(col0 + srow) * K + schunk * 8;

    f32x4 acc[2][2];
    #pragma unroll
    for (int i = 0; i < 2; ++i)
        #pragma unroll
        for (int j = 0; j < 2; ++j)
            #pragma unroll
            for (int r = 0; r < 4; ++r) acc[i][j][r] = 0.f;

    for (int k0 = 0; k0 < K; k0 += 32) {
        float4 ax0 = ((const float4*)(aptr + k0))[0];
        float4 ax1 = ((const float4*)(aptr + k0))[1];
        uint4  bvh = *(const uint4*)(bptrh + k0);
        uint4  bvl = *(const uint4*)(bptrl + k0);
        ushort4 h0, h1, l0, l1;
        h0.x = f2bf_rne(ax0.x); l0.x = f2bf_rne(ax0.x - bf2f(h0.x));
        h0.y = f2bf_rne(ax0.y); l0.y = f2bf_rne(ax0.y - bf2f(h0.y));
        h0.z = f2bf_rne(ax0.z); l0.z = f2bf_rne(ax0.z - bf2f(h0.z));
        h0.w = f2bf_rne(ax0.w); l0.w = f2bf_rne(ax0.w - bf2f(h0.w));
        h1.x = f2bf_rne(ax1.x); l1.x = f2bf_rne(ax1.x - bf2f(h1.x));
        h1.y = f2bf_rne(ax1.y); l1.y = f2bf_rne(ax1.y - bf2f(h1.y));
        h1.z = f2bf_rne(ax1.z); l1.z = f2bf_rne(ax1.z - bf2f(h1.z));
        h1.w = f2bf_rne(ax1.w); l1.w = f2bf_rne(ax1.w - bf2f(h1.w));
        *(ushort4*)&As[0][srow][schunk * 8]     = h0;
        *(ushort4*)&As[0][srow][schunk * 8 + 4] = h1;
        *(ushort4*)&As[1][srow][schunk * 8]     = l0;
        *(ushort4*)&As[1][srow][schunk * 8 + 4] = l1;
        *(uint4*)&Bs[0][srow][schunk * 8] = bvh;
        *(uint4*)&Bs[1][srow][schunk * 8] = bvl;
        __syncthreads();

        bf16x8 af[2], bf[2], afl[2], bfl[2];
        #pragma unroll
        for (int i = 0; i < 2; ++i) {
            af[i]  = *(const bf16x8*)&As[0][wm * 32 + i * 16 + m16][quad * 8];
            bf[i]  = *(const bf16x8*)&Bs[0][wn * 32 + i * 16 + m16][quad * 8];
            afl[i] = *(const bf16x8*)&As[1][wm * 32 + i * 16 + m16][quad * 8];
            bfl[i] = *(const bf16x8*)&Bs[1][wn * 32 + i * 16 + m16][quad * 8];
        }
        #pragma unroll
        for (int i = 0; i < 2; ++i)
            #pragma unroll
            for (int j = 0; j < 2; ++j) {
                acc[i][j] = __builtin_amdgcn_mfma_f32_16x16x32_bf16(af[i], bf[j], acc[i][j], 0, 0, 0);
                acc[i][j] = __builtin_amdgcn_mfma_f32_16x16x32_bf16(af[i], bfl[j], acc[i][j], 0, 0, 0);
                acc[i][j] = __builtin_amdgcn_mfma_f32_16x16x32_bf16(afl[i], bf[j], acc[i][j], 0, 0, 0);
            }
        __syncthreads();
    }

    #pragma unroll
    for (int i = 0; i < 2; ++i)
        #pragma unroll
        for (int j = 0; j < 2; ++j) {
            int r0 = row0 + wm * 32 + i * 16 + quad * 4;
            int c = col0 + wn * 32 + j * 16 + m16;
            #pragma unroll
            for (int reg = 0; reg < 4; ++reg)
                C[(size_t)(r0 + reg) * N + c] = acc[i][j][reg];
        }
}

// ---------------------------------------------------------------------------
// Final split GEMM: out = ctx(hi/lo) @ Wo(hi/lo), 512x512x512 -> fp32.
// ---------------------------------------------------------------------------
__global__ __launch_bounds__(256) void gemm_out(
    const ushort* __restrict__ Ah, const ushort* __restrict__ Al,
    const ushort* __restrict__ Bh, const ushort* __restrict__ Bl,
    float* __restrict__ C)
{
    const int K = 512, N = 512;
    __shared__ ushort As[2][64][40];
    __shared__ ushort Bs[2][64][40];
    const int tid = threadIdx.x;
    const int row0 = blockIdx.y * 64, col0 = blockIdx.x * 64;
    const int wave = tid >> 6, lane = tid & 63;
    const int wm = wave & 1, wn = wave >> 1;
    const int m16 = lane & 15, quad = lane >> 4;
    const int srow = tid >> 2, schunk = tid & 3;

    f32x4 acc[2][2];
    #pragma unroll
    for (int i = 0; i < 2; ++i)
        #pragma unroll
        for (int j = 0; j < 2; ++j)
            #pragma unroll
            for (int r = 0; r < 4; ++r) acc[i][j][r] = 0.f;

    for (int k0 = 0; k0 < K; k0 += 32) {
        const size_t aoff = (size_t)(row0 + srow) * K + k0 + schunk * 8;
        const size_t boff = (size_t)(col0 + srow) * K + k0 + schunk * 8;
        *(uint4*)&As[0][srow][schunk * 8] = *(const uint4*)(Ah + aoff);
        *(uint4*)&Bs[0][srow][schunk * 8] = *(const uint4*)(Bh + boff);
        *(uint4*)&As[1][srow][schunk * 8] = *(const uint4*)(Al + aoff);
        *(uint4*)&Bs[1][srow][schunk * 8] = *(const uint4*)(Bl + boff);
        __syncthreads();

        bf16x8 af[2], bf[2], afl[2], bfl[2];
        #pragma unroll
        for (int i = 0; i < 2; ++i) {
            af[i]  = *(const bf16x8*)&As[0][wm * 32 + i * 16 + m16][quad * 8];
            bf[i]  = *(const bf16x8*)&Bs[0][wn * 32 + i * 16 + m16][quad * 8];
            afl[i] = *(const bf16x8*)&As[1][wm * 32 + i * 16 + m16][quad * 8];
            bfl[i] = *(const bf16x8*)&Bs[1][wn * 32 + i * 16 + m16][quad * 8];
        }
        #pragma unroll
        for (int i = 0; i < 2; ++i)
            #pragma unroll
            for (int j = 0; j < 2; ++j) {
                acc[i][j] = __builtin_amdgcn_mfma_f32_16x16x32_bf16(af[i], bf[j], acc[i][j], 0, 0, 0);
                acc[i][j] = __builtin_amdgcn_mfma_f32_16x16x32_bf16(af[i], bfl[j], acc[i][j], 0, 0, 0);
                acc[i][j] = __builtin_amdgcn_mfma_f32_16x16x32_bf16(afl[i], bf[j], acc[i][j], 0, 0, 0);
            }
        __syncthreads();
    }

    #pragma unroll
    for (int i = 0; i < 2; ++i)
        #pragma unroll
        for (int j = 0; j < 2; ++j) {
            int r0 = row0 + wm * 32 + i * 16 + quad * 4;
            int c = col0 + wn * 32 + j * 16 + m16;
            #pragma unroll
            for (int reg = 0; reg < 4; ++reg)
                C[(size_t)(r0 + reg) * N + c] = acc[i][j][reg];
        }
}

// ---------------------------------------------------------------------------
// Merged token projections (one launch, z selects):
// z=0: k_tok[(s,t),(h,d)] = tok_keys @ Wk_token (64x256 tile)
// z=1: vT[(h,d),(b,s,t)]  = Wv^T @ values^T     (256x64 tile)
// fp32 inputs converted to bf16 inline; last-16 row map r->(r>>4)*64+48+(r&15).
// ---------------------------------------------------------------------------
__global__ __launch_bounds__(256) void gemm_tokv(
    const float* __restrict__ token_keys, const float* __restrict__ values,
    const ushort* __restrict__ wkt_h, const ushort* __restrict__ wv_h,
    ushort* __restrict__ k_tok, ushort* __restrict__ vT)
{
    const int K = 512;
    __shared__ ushort sBig[256][40];
    __shared__ ushort sSml[64][40];
    const int tid = threadIdx.x;
    const int wave = tid >> 6, lane = tid & 63;
    const int m16 = lane & 15, quad = lane >> 4;
    const int srow = tid >> 2, schunk = tid & 3;

    f32x4 acc[4][4];
    #pragma unroll
    for (int i = 0; i < 4; ++i)
        #pragma unroll
        for (int j = 0; j < 4; ++j)
            #pragma unroll
            for (int rr = 0; rr < 4; ++rr) acc[i][j][rr] = 0.f;

    if (blockIdx.z == 0) {
        const int row0 = blockIdx.y * 64, col0 = blockIdx.x * 256;
        const int r = row0 + srow;
        const size_t arow = (size_t)((r >> 4) * 64 + 48 + (r & 15)) * K;

        for (int k0 = 0; k0 < K; k0 += 32) {
            const float* ap = token_keys + arow + k0 + schunk * 8;
            float4 x0 = ((const float4*)ap)[0];
            float4 x1 = ((const float4*)ap)[1];
            ushort4 h0, h1;
            h0.x = f2bf_rne(x0.x); h0.y = f2bf_rne(x0.y);
            h0.z = f2bf_rne(x0.z); h0.w = f2bf_rne(x0.w);
            h1.x = f2bf_rne(x1.x); h1.y = f2bf_rne(x1.y);
            h1.z = f2bf_rne(x1.z); h1.w = f2bf_rne(x1.w);
            *(ushort4*)&sSml[srow][schunk * 8] = h0;
            *(ushort4*)&sSml[srow][schunk * 8 + 4] = h1;
            #pragma unroll
            for (int i = 0; i < 4; ++i) {
                int v = tid + i * 256;
                *(uint4*)&sBig[v >> 2][(v & 3) * 8] =
                    *(const uint4*)(wkt_h + (size_t)(col0 + (v >> 2)) * K + k0 + (v & 3) * 8);
            }
            __syncthreads();

            bf16x8 af[4], bf[4];
            #pragma unroll
            for (int i = 0; i < 4; ++i) {
                af[i] = *(const bf16x8*)&sSml[i * 16 + m16][quad * 8];
                bf[i] = *(const bf16x8*)&sBig[wave * 64 + i * 16 + m16][quad * 8];
            }
            #pragma unroll
            for (int i = 0; i < 4; ++i)
                #pragma unroll
                for (int j = 0; j < 4; ++j)
                    acc[i][j] = __builtin_amdgcn_mfma_f32_16x16x32_bf16(af[i], bf[j], acc[i][j], 0, 0, 0);
            __syncthreads();
        }

        #pragma unroll
        for (int i = 0; i < 4; ++i)
            #pragma unroll
            for (int j = 0; j < 4; ++j) {
                int r0 = row0 + i * 16 + quad * 4;
                int c = col0 + wave * 64 + j * 16 + m16;
                #pragma unroll
                for (int reg = 0; reg < 4; ++reg)
                    k_tok[(size_t)(r0 + reg) * 512 + c] = f2bf_rne(acc[i][j][reg]);
            }
    } else {
        const int row0m = blockIdx.x * 256, col0n = blockIdx.y * 64;
        const int n = col0n + srow;
        const size_t brow = (size_t)((n >> 4) * 64 + 48 + (n & 15)) * K;

        for (int k0 = 0; k0 < K; k0 += 32) {
            const float* bp = values + brow + k0 + schunk * 8;
            float4 x0 = ((const float4*)bp)[0];
            float4 x1 = ((const float4*)bp)[1];
            ushort4 h0, h1;
            h0.x = f2bf_rne(x0.x); h0.y = f2bf_rne(x0.y);
            h0.z = f2bf_rne(x0.z); h0.w = f2bf_rne(x0.w);
            h1.x = f2bf_rne(x1.x); h1.y = f2bf_rne(x1.y);
            h1.z = f2bf_rne(x1.z); h1.w = f2bf_rne(x1.w);
            *(ushort4*)&sSml[srow][schunk * 8] = h0;
            *(ushort4*)&sSml[srow][schunk * 8 + 4] = h1;
            #pragma unroll
            for (int i = 0; i < 4; ++i) {
                int v = tid + i * 256;
                *(uint4*)&sBig[v >> 2][(v & 3) * 8] =
                    *(const uint4*)(wv_h + (size_t)(row0m + (v >> 2)) * K + k0 + (v & 3) * 8);
            }
            __syncthreads();

            bf16x8 af[4], bf[4];
            #pragma unroll
            for (int i = 0; i < 4; ++i) {
                af[i] = *(const bf16x8*)&sBig[wave * 64 + i * 16 + m16][quad * 8];
                bf[i] = *(const bf16x8*)&sSml[i * 16 + m16][quad * 8];
            }
            #pragma unroll
            for (int i = 0; i < 4; ++i)
                #pragma unroll
                for (int j = 0; j < 4; ++j)
                    acc[i][j] = __builtin_amdgcn_mfma_f32_16x16x32_bf16(af[i], bf[j], acc[i][j], 0, 0, 0);
            __syncthreads();
        }

        #pragma unroll
        for (int i = 0; i < 4; ++i)
            #pragma unroll
            for (int j = 0; j < 4; ++j) {
                int m = row0m + wave * 64 + i * 16 + quad * 4;
                int c = col0n + j * 16 + m16;
                #pragma unroll
                for (int reg = 0; reg < 4; ++reg)
                    vT[(size_t)(m + reg) * 8192 + c] = f2bf_rne(acc[i][j][reg]);
            }
    }
}

// ---------------------------------------------------------------------------
// Dense MFMA attention, low-barrier version. One 256-thread wg per (b,h,qt).
// Stat: rank-scan top-8 (selection identical to lax.top_k). Token scores:
// B-frags loaded DIRECTLY from global k_tok (no LDS staging, no barriers in
// the score loop). Comb hi/lo -> LDS (layout transform) -> PV vs vT.
// 7 barriers/block total (was ~19 in R7).
// ---------------------------------------------------------------------------
__global__ __launch_bounds__(256) void attend_mfma(
    const float* __restrict__ q_stat, const float* __restrict__ k_stat,
    const float* __restrict__ q_tokf, const ushort* __restrict__ k_tok,
    const ushort* __restrict__ vT, const int* __restrict__ valid_lens,
    ushort* __restrict__ ctx_hi, ushort* __restrict__ ctx_lo)
{
    const int wg = blockIdx.x;
    const int b = wg >> 5, h = (wg >> 2) & 7, qt = wg & 3;
    const int tid = threadIdx.x, wave = tid >> 6, lane = tid & 63;
    const int m16 = lane & 15, quad = lane >> 4;

    __shared__ float  sQs[16][64];       // q_stat tile
    __shared__ ushort sQt[2][16][72];    // q_tok hi/lo bf16
    __shared__ float  sSc[16][64];       // stat scores (per q row)
    __shared__ float  sW[16][64];        // per-q segment weights
    __shared__ ushort sCb[2][16][520];   // comb hi/lo for one 512-k half

    // ---- stage q tiles ----
    {
        int row = tid >> 4, c4 = tid & 15;
        const size_t qrow = (size_t)(b * 64 + qt * 16 + row) * 512 + h * 64;
        float4 xs = *(const float4*)(q_stat + qrow + c4 * 4);
        *(float4*)&sQs[row][c4 * 4] = xs;
        float4 xt = *(const float4*)(q_tokf + qrow + c4 * 4);
        ushort4 hh, ll;
        hh.x = f2bf_rne(xt.x); ll.x = f2bf_rne(xt.x - bf2f(hh.x));
        hh.y = f2bf_rne(xt.y); ll.y = f2bf_rne(xt.y - bf2f(hh.y));
        hh.z = f2bf_rne(xt.z); ll.z = f2bf_rne(xt.z - bf2f(hh.z));
        hh.w = f2bf_rne(xt.w); ll.w = f2bf_rne(xt.w - bf2f(hh.w));
        *(ushort4*)&sQt[0][row][c4 * 4] = hh;
        *(ushort4*)&sQt[1][row][c4 * 4] = ll;
    }
    __syncthreads();

    bf16x8 aQh[2], aQl[2];
    #pragma unroll
    for (int ks = 0; ks < 2; ++ks) {
        aQh[ks] = *(const bf16x8*)&sQt[0][m16][ks * 32 + quad * 8];
        aQl[ks] = *(const bf16x8*)&sQt[1][m16][ks * 32 + quad * 8];
    }

    // ---- stat scores (lane = segment; wave handles q = wave*4..+3) ----
    const int vlen = valid_lens[b];
    #pragma unroll
    for (int qq = 0; qq < 4; ++qq) {
        const int q = wave * 4 + qq;
        const float4* kr = (const float4*)(k_stat + (size_t)(b * SS + lane) * NHID + h * DH);
        const float4* sq4 = (const float4*)&sQs[q][0];
        float sc = 0.f;
        #pragma unroll
        for (int i = 0; i < 16; ++i) {
            float4 a = sq4[i], kk = kr[i];
            sc += a.x * kk.x + a.y * kk.y + a.z * kk.z + a.w * kk.w;
        }
        sc *= 0.125f;
        if (lane >= vlen) sc = -1e6f;
        sSc[q][lane] = sc;
    }
    __syncthreads();

    // ---- rank-scan top-8 + softmax weights (kept iff rank < 8) ----
    #pragma unroll
    for (int qq = 0; qq < 4; ++qq) {
        const int q = wave * 4 + qq;
        const float sc = sSc[q][lane];
        const float4* row4 = (const float4*)&sSc[q][0];
        int rank = 0;
        float mx = -3e38f;
        #pragma unroll
        for (int i = 0; i < 16; ++i) {
            float4 v = row4[i];
            mx = fmaxf(mx, fmaxf(fmaxf(v.x, v.y), fmaxf(v.z, v.w)));
            rank += (v.x > sc || (v.x == sc && (i * 4 + 0) < lane)) ? 1 : 0;
            rank += (v.y > sc || (v.y == sc && (i * 4 + 1) < lane)) ? 1 : 0;
            rank += (v.z > sc || (v.z == sc && (i * 4 + 2) < lane)) ? 1 : 0;
            rank += (v.w > sc || (v.w == sc && (i * 4 + 3) < lane)) ? 1 : 0;
        }
        float e = (rank < STAT_K) ? __expf(sc - mx) : 0.f;
        float s = e;
        s += __shfl_xor(s, 1);  s += __shfl_xor(s, 2);
        s += __shfl_xor(s, 4);  s += __shfl_xor(s, 8);
        s += __shfl_xor(s, 16); s += __shfl_xor(s, 32);
        sW[q][lane] = e / s;
    }
    __syncthreads();

    // ---- token scores + softmax + comb + PV, two 512-k halves ----
    f32x4 oacc;
    #pragma unroll
    for (int r = 0; r < 4; ++r) oacc[r] = 0.f;

    const ushort* vrow = vT + (size_t)(h * 64 + wave * 16 + m16) * 8192
                            + (size_t)b * 1024 + quad * 8;

    for (int half = 0; half < 2; ++half) {
        // comb production: wave handles segs (half*32 + wave*8 + si), no LDS
        // staging for K -- B-frags loaded directly from global (L2/L3-hot).
        #pragma unroll
        for (int si = 0; si < 8; ++si) {
            const int sl = wave * 8 + si;            // seg within half
            const int sg = half * 32 + sl;           // global seg
            const ushort* kb = k_tok
                + (size_t)(b * 1024 + sg * 16 + m16) * 512 + h * 64 + quad * 8;
            bf16x8 b0 = *(const bf16x8*)kb;
            bf16x8 b1 = *(const bf16x8*)(kb + 32);
            f32x4 c;
            #pragma unroll
            for (int r = 0; r < 4; ++r) c[r] = 0.f;
            c = __builtin_amdgcn_mfma_f32_16x16x32_bf16(aQh[0], b0, c, 0, 0, 0);
            c = __builtin_amdgcn_mfma_f32_16x16x32_bf16(aQl[0], b0, c, 0, 0, 0);
            c = __builtin_amdgcn_mfma_f32_16x16x32_bf16(aQh[1], b1, c, 0, 0, 0);
            c = __builtin_amdgcn_mfma_f32_16x16x32_bf16(aQl[1], b1, c, 0, 0, 0);

            const int klb = sl * 16 + m16;
            #pragma unroll
            for (int r = 0; r < 4; ++r) {
                float v = c[r] * 0.125f;
                float m = v;
                m = fmaxf(m, __shfl_xor(m, 1));
                m = fmaxf(m, __shfl_xor(m, 2));
                m = fmaxf(m, __shfl_xor(m, 4));
                m = fmaxf(m, __shfl_xor(m, 8));
                float e = __expf(v - m);
                float s = e;
                s += __shfl_xor(s, 1);
                s += __shfl_xor(s, 2);
                s += __shfl_xor(s, 4);
                s += __shfl_xor(s, 8);
                float wt = (e / s) * sW[quad * 4 + r][sg];
                ushort ch = f2bf_rne(wt);
                sCb[0][quad * 4 + r][klb] = ch;
                sCb[1][quad * 4 + r][klb] = f2bf_rne(wt - bf2f(ch));
            }
        }
        __syncthreads();   // comb half complete

        #pragma unroll
        for (int ks = 0; ks < 16; ++ks) {
            bf16x8 bv = *(const bf16x8*)(vrow + half * 512 + ks * 32);
            bf16x8 ah = *(const bf16x8*)&sCb[0][m16][ks * 32 + quad * 8];
            bf16x8 al = *(const bf16x8*)&sCb[1][m16][ks * 32 + quad * 8];
            oacc = __builtin_amdgcn_mfma_f32_16x16x32_bf16(ah, bv, oacc, 0, 0, 0);
            oacc = __builtin_amdgcn_mfma_f32_16x16x32_bf16(al, bv, oacc, 0, 0, 0);
        }
        __syncthreads();   // protect sCb before next half overwrites
    }

    // ---- epilogue: ctx hi/lo ----
    #pragma unroll
    for (int r = 0; r < 4; ++r) {
        const size_t o = (size_t)(b * 64 + qt * 16 + quad * 4 + r) * 512
                       + h * 64 + wave * 16 + m16;
        ushort hh = f2bf_rne(oacc[r]);
        ctx_hi[o] = hh;
        ctx_lo[o] = f2bf_rne(oacc[r] - bf2f(hh));
    }
}

extern "C" void kernel_launch(void* const* d_in, const int* in_sizes, int n_in,
                              void* d_out, int out_size, void* d_ws, size_t ws_size,
                              hipStream_t stream) {
    const float* queries    = (const float*)d_in[0];
    const float* stat_keys  = (const float*)d_in[1];
    const float* token_keys = (const float*)d_in[2];
    const float* values     = (const float*)d_in[3];
    const int*   valid_lens = (const int*)d_in[4];
    const float* Wq_stat    = (const float*)d_in[5];
    const float* Wq_token   = (const float*)d_in[6];
    const float* Wk_stat    = (const float*)d_in[7];
    const float* Wk_token   = (const float*)d_in[8];
    const float* Wv         = (const float*)d_in[9];
    const float* Wo         = (const float*)d_in[10];

    char* w = (char*)d_ws;
    ushort* wT      = (ushort*)(w + 0);            // 6 x (hi+lo) x 262144 ush
    float*  q_stat  = (float*)(w + 6291456);
    float*  k_stat  = (float*)(w + 7340032);
    float*  q_tokf  = (float*)(w + 8388608);
    ushort* k_tok   = (ushort*)(w + 9437184);      // bf16 [8192,512]
    ushort* vT      = (ushort*)(w + 17825792);     // bf16 [512,8192]
    ushort* ctx_hi  = (ushort*)(w + 26214400);
    ushort* ctx_lo  = ctx_hi + 262144;

    ushort* wkt_h = wT + 3 * 524288;
    ushort* wv_h  = wT + 4 * 524288;
    ushort* wo_h  = wT + 5 * 524288, *wo_l = wo_h + 262144;

    // 1. weight transpose+split
    conv_w<<<dim3(16, 16, 6), 256, 0, stream>>>(
        Wq_stat, Wk_stat, Wq_token, Wk_token, Wv, Wo, wT);

    // 2. q_stat / k_stat / q_tok projections (fp32-equivalent)
    gemm_split3<<<dim3(8, 8, 3), 256, 0, stream>>>(
        queries, stat_keys, wT, q_stat, k_stat, q_tokf);

    // 3. K-token + V-transposed projections in one launch
    gemm_tokv<<<dim3(2, 128, 2), 256, 0, stream>>>(
        token_keys, values, wkt_h, wv_h, k_tok, vT);

    // 4. dense MFMA attention (rank-scan top-8 + token softmax + PV)
    attend_mfma<<<256, 256, 0, stream>>>(
        q_stat, k_stat, q_tokf, k_tok, vT, valid_lens, ctx_hi, ctx_lo);

    // 5. output projection
    gemm_out<<<dim3(8, 8), 256, 0, stream>>>(
        ctx_hi, ctx_lo, wo_h, wo_l, (float*)d_out);
}